// Round 4
// baseline (54.058 us; speedup 1.0000x reference)
//
#include <hip/hip_runtime.h>

// Problem constants (from reference setup_inputs): N=64, D=64, S=64, m=128
constexpr int N_ = 64;
constexpr int D_ = 64;
constexpr int S_ = 64;
constexpr int M_ = 128;

typedef float fv4 __attribute__((ext_vector_type(4)));

// ---------------------------------------------------------------------------
// Kernel 0 (tiny, 64 blocks): rank-1 scalar terms.
//   sumx[n,d] = sum_i x[n,d,i]
//   t2ws[n,s] = (sum_d c1[d,s] * sumx[n,d]) / m
//   scws[n,s] = (sum_d c4[d,s] * sumx[n,d]) / m + bias[s]
// ---------------------------------------------------------------------------
__global__ __launch_bounds__(256) void l12_scalars(
    const float* __restrict__ x,       // [N, D, M]
    const float* __restrict__ coeffs,  // [D, S, 5]
    const float* __restrict__ bias,    // [S]
    float* __restrict__ t2ws,          // [N*S]
    float* __restrict__ scws)          // [N*S]
{
    const int n = blockIdx.x;
    const int t = threadIdx.x;

    __shared__ float sum4[D_][4];
    __shared__ float sumx[D_];

    // Partial row-sums of x[n]: thread (d = t>>2, q = t&3) sums 32 elems.
    const int d = t >> 2, q = t & 3;
    const fv4* xp = reinterpret_cast<const fv4*>(
        x + ((size_t)n * D_ + d) * M_ + q * 32);
    float s = 0.f;
    #pragma unroll
    for (int k = 0; k < 8; ++k) {
        fv4 v = xp[k];
        s += v.x + v.y + v.z + v.w;
    }
    sum4[d][q] = s;
    __syncthreads();

    if (t < D_) sumx[t] = sum4[t][0] + sum4[t][1] + sum4[t][2] + sum4[t][3];
    __syncthreads();

    if (t < S_) {   // t = s
        float a2 = 0.f, a5 = 0.f;
        #pragma unroll 8
        for (int dd = 0; dd < D_; ++dd) {
            const float* cp = coeffs + ((size_t)dd * S_ + t) * 5;
            a2 += cp[1] * sumx[dd];
            a5 += cp[4] * sumx[dd];
        }
        const float inv_m = 1.0f / (float)M_;
        t2ws[n * S_ + t] = a2 * inv_m;
        scws[n * S_ + t] = a5 * inv_m + bias[t];
    }
}

// ---------------------------------------------------------------------------
// Main kernel: one block per (n,s); 3-dot contraction + 256 MiB tile stream.
// out[n,s,i,j] = CB[i] + A3[j] + (i==j)*DG[i]
//   A3[j] = sum_d c2[d,s] x[n,d,j]
//   CB[i] = sum_d c3[d,s] x[n,d,i] + scws[n,s]
//   DG[i] = sum_d c0[d,s] x[n,d,i] + t2ws[n,s]
// ---------------------------------------------------------------------------
__global__ __launch_bounds__(256) void l12_fused(
    const float* __restrict__ x,       // [N, D, M]
    const float* __restrict__ coeffs,  // [D, S, 5]
    const float* __restrict__ t2ws,    // [N*S]
    const float* __restrict__ scws,    // [N*S]
    float* __restrict__ out)           // [N, S, M, M]
{
    const int blk = blockIdx.x;        // n*S + s
    const int n   = blk >> 6;
    const int s   = blk & (S_ - 1);
    const int t   = threadIdx.x;       // 0..255
    const int i   = t & (M_ - 1);      // 0..127
    const int half = t >> 7;           // D-split

    __shared__ float sh_c[D_][3];      // c0, c2, c3 for this s
    __shared__ float part[3][2][M_];
    __shared__ __align__(16) float A3[M_];
    __shared__ float CB[M_];
    __shared__ float DG[M_];

    if (t < D_) {
        const float* cp = coeffs + ((size_t)t * S_ + s) * 5;
        sh_c[t][0] = cp[0];
        sh_c[t][1] = cp[2];
        sh_c[t][2] = cp[3];
    }
    __syncthreads();

    // Three contractions over D, split 2-way across the 256 threads.
    float r0 = 0.f, r2 = 0.f, r3 = 0.f;
    const float* xp = x + ((size_t)(n * D_) + half * (D_ / 2)) * M_ + i;
    #pragma unroll
    for (int dd = 0; dd < D_ / 2; ++dd) {
        float xv = xp[(size_t)dd * M_];   // coalesced, L2-resident
        int d2 = half * (D_ / 2) + dd;
        r0 += sh_c[d2][0] * xv;
        r2 += sh_c[d2][1] * xv;
        r3 += sh_c[d2][2] * xv;
    }
    part[0][half][i] = r0;
    part[1][half][i] = r2;
    part[2][half][i] = r3;
    __syncthreads();

    if (t < M_) {
        float t2v = t2ws[blk];
        float scv = scws[blk];
        DG[i] = part[0][0][i] + part[0][1][i] + t2v;
        A3[i] = part[1][0][i] + part[1][1][i];
        CB[i] = part[2][0][i] + part[2][1][i] + scv;
    }
    __syncthreads();

    // Stream the 128x128 tile; fully coalesced fv4 stores, static indexing.
    fv4* outp = reinterpret_cast<fv4*>(out + (size_t)blk * (M_ * M_));
    const int j4 = (t & 31) * 4;
    const fv4 a3v = *reinterpret_cast<const fv4*>(&A3[j4]);

    #pragma unroll
    for (int it = 0; it < 16; ++it) {
        int l   = it * 256 + t;      // fv4 index within tile (0..4095)
        int row = l >> 5;            // 32 fv4 per row
        float base = CB[row];
        float dg   = DG[row];
        fv4 v;
        v.x = base + a3v.x + ((row == j4 + 0) ? dg : 0.f);
        v.y = base + a3v.y + ((row == j4 + 1) ? dg : 0.f);
        v.z = base + a3v.z + ((row == j4 + 2) ? dg : 0.f);
        v.w = base + a3v.w + ((row == j4 + 3) ? dg : 0.f);
        outp[l] = v;
    }
}

extern "C" void kernel_launch(void* const* d_in, const int* in_sizes, int n_in,
                              void* d_out, int out_size, void* d_ws, size_t ws_size,
                              hipStream_t stream) {
    const float* x      = (const float*)d_in[0];  // [64,64,128]
    const float* coeffs = (const float*)d_in[1];  // [64,64,5]
    const float* bias   = (const float*)d_in[2];  // [1,64,1,1] -> 64
    float* out          = (float*)d_out;          // [64,64,128,128]

    float* t2ws = (float*)d_ws;                   // [4096]
    float* scws = t2ws + (size_t)N_ * S_;         // [4096]

    l12_scalars<<<dim3(N_), dim3(256), 0, stream>>>(x, coeffs, bias, t2ws, scws);
    l12_fused  <<<dim3(N_ * S_), dim3(256), 0, stream>>>(x, coeffs, t2ws, scws, out);
}